// Round 1
// baseline (1693.840 us; speedup 1.0000x reference)
//
#include <hip/hip_runtime.h>
#include <hip/hip_bf16.h>

#define N_TOK 32768
#define INC   256     // input channels
#define HDIM  256     // H*D
#define NH    4
#define DH    64
#define NP    64      // partitions
#define SP    512     // partition size
#define NM    4       // pool seeds
#define NREPS 256     // P*M
#define INV_SCALE 0.125f

// ---------------------------------------------------------------------------
// Kernel A: QKV projection.  C = x @ W^T + b for W in {Wq,Wk,Wv}.
// grid (512 row-tiles, 4 col-tiles, 3 matrices), block 256.
// BM=64, BN=64, BK=32; each thread computes 4x4.
// ---------------------------------------------------------------------------
__global__ __launch_bounds__(256) void qkv_gemm(
    const float* __restrict__ x,
    const float* __restrict__ Wq, const float* __restrict__ bq,
    const float* __restrict__ Wk, const float* __restrict__ bk,
    const float* __restrict__ Wv, const float* __restrict__ bv,
    float* __restrict__ Q, float* __restrict__ K, float* __restrict__ V)
{
    const float* W; const float* bias; float* out;
    if (blockIdx.z == 0)      { W = Wq; bias = bq; out = Q; }
    else if (blockIdx.z == 1) { W = Wk; bias = bk; out = K; }
    else                      { W = Wv; bias = bv; out = V; }

    __shared__ float xs[64][36];   // [m][k], pad 36 for aligned float4 + 2-way-max banks
    __shared__ float wsh[64][36];  // [n][k]

    const int rowBase = blockIdx.x * 64;
    const int colBase = blockIdx.y * 64;
    const int tid = threadIdx.x;
    const int r = tid >> 4;   // 0..15 (within wave: 0..3)
    const int c = tid & 15;   // 0..15 -> coalesced stores vary c fastest

    float acc[4][4];
    #pragma unroll
    for (int a = 0; a < 4; ++a)
        #pragma unroll
        for (int b = 0; b < 4; ++b) acc[a][b] = 0.f;

    for (int k0 = 0; k0 < INC; k0 += 32) {
        __syncthreads();
        #pragma unroll
        for (int it = 0; it < 2; ++it) {
            int fidx = tid + 256 * it;       // 0..511
            int m  = fidx >> 3;              // 0..63
            int k4 = (fidx & 7) * 4;         // 0..28
            *(float4*)&xs[m][k4]  = *(const float4*)&x[(size_t)(rowBase + m) * INC + k0 + k4];
            *(float4*)&wsh[m][k4] = *(const float4*)&W[(size_t)(colBase + m) * INC + k0 + k4];
        }
        __syncthreads();
        #pragma unroll
        for (int kk = 0; kk < 32; kk += 4) {
            float4 xa[4], wb[4];
            #pragma unroll
            for (int a = 0; a < 4; ++a) xa[a] = *(const float4*)&xs[r + 16 * a][kk];
            #pragma unroll
            for (int b = 0; b < 4; ++b) wb[b] = *(const float4*)&wsh[c + 16 * b][kk];
            #pragma unroll
            for (int a = 0; a < 4; ++a)
                #pragma unroll
                for (int b = 0; b < 4; ++b)
                    acc[a][b] += xa[a].x * wb[b].x + xa[a].y * wb[b].y
                               + xa[a].z * wb[b].z + xa[a].w * wb[b].w;
        }
    }

    float bvv[4];
    #pragma unroll
    for (int b = 0; b < 4; ++b) bvv[b] = bias[colBase + c + 16 * b];
    #pragma unroll
    for (int a = 0; a < 4; ++a) {
        size_t row = (size_t)(rowBase + r + 16 * a) * HDIM;
        #pragma unroll
        for (int b = 0; b < 4; ++b)
            out[row + colBase + c + 16 * b] = acc[a][b] + bvv[b];
    }
}

// ---------------------------------------------------------------------------
// Kernel C: seed pooling -> reps_k, reps_v.  grid (64,4), block 512.
// ---------------------------------------------------------------------------
__global__ __launch_bounds__(512) void pool_reps(
    const float* __restrict__ K, const float* __restrict__ V,
    const int* __restrict__ idx, const float* __restrict__ seeds,
    float* __restrict__ reps_k, float* __restrict__ reps_v)
{
    const int p = blockIdx.x, h = blockIdx.y;
    const int tid = threadIdx.x;
    __shared__ float pexp[NM][SP];
    __shared__ float sums[NM];
    __shared__ float sred[NM][8];
    __shared__ float sd[NM][DH];
    __shared__ int   sidx[SP];

    if (tid < NM * DH) {
        int m = tid >> 6, d = tid & 63;
        sd[m][d] = seeds[(size_t)(m * NH + h) * DH + d];
    }
    sidx[tid] = idx[p * SP + tid];
    __syncthreads();

    // scores + exp for this thread's token
    const int n_s = sidx[tid];
    float kr[64];
    #pragma unroll
    for (int d4 = 0; d4 < 16; ++d4)
        *(float4*)&kr[d4 * 4] = *(const float4*)&K[(size_t)n_s * HDIM + h * DH + d4 * 4];

    float e[NM];
    #pragma unroll
    for (int m = 0; m < NM; ++m) {
        float s = 0.f;
        #pragma unroll
        for (int d = 0; d < 64; ++d) s += kr[d] * sd[m][d];
        e[m] = __expf(s * INV_SCALE);
        pexp[m][tid] = e[m];
    }
    // block reduction of sums
    const int lane = tid & 63, w = tid >> 6;
    #pragma unroll
    for (int m = 0; m < NM; ++m) {
        float v = e[m];
        #pragma unroll
        for (int off = 32; off >= 1; off >>= 1) v += __shfl_xor(v, off);
        if (lane == 0) sred[m][w] = v;
    }
    __syncthreads();
    if (tid < NM) {
        float s = 0.f;
        #pragma unroll
        for (int i = 0; i < 8; ++i) s += sred[tid][i];
        sums[tid] = s;
    }
    __syncthreads();

    // accumulate reps: wave w -> (m = w>>1, kv = w&1), lane = dim
    const int m = w >> 1, kv = w & 1, d = lane;
    const float* src = kv ? V : K;
    float acc = 0.f;
    #pragma unroll 4
    for (int s = 0; s < SP; ++s)
        acc += pexp[m][s] * src[(size_t)sidx[s] * HDIM + h * DH + d];
    float* dst = kv ? reps_v : reps_k;
    dst[(size_t)(p * NM + m) * HDIM + h * DH + d] = acc / sums[m];
}

// ---------------------------------------------------------------------------
// Kernel B: local attention within partitions, fused alpha*mean_h into d_out.
// grid (64,4), block 512.  Thread owns 4 q-rows x 16 dims; quad shuffles
// reduce scores.  No-max softmax (scores bounded ~|2|).
// ---------------------------------------------------------------------------
__global__ __launch_bounds__(512) void local_attn(
    const float* __restrict__ Q, const float* __restrict__ K, const float* __restrict__ V,
    const int* __restrict__ idx, const float* __restrict__ bscore,
    const float* __restrict__ alpha_logit, const float* __restrict__ bweight,
    float* __restrict__ dout)
{
    const int p = blockIdx.x, h = blockIdx.y;
    const int tid = threadIdx.x;
    const int dq = tid & 3;        // dim quarter
    const int qg = tid >> 2;       // 0..127

    __shared__ float Ks[64][68];
    __shared__ float Vs[64][68];

    int nq[4];
    float Qr[4][16], outv[4][16], ssum[4];
    #pragma unroll
    for (int i = 0; i < 4; ++i) {
        nq[i] = idx[p * SP + qg + 128 * i];
        const float* qp = &Q[(size_t)nq[i] * HDIM + h * DH + dq * 16];
        #pragma unroll
        for (int d4 = 0; d4 < 4; ++d4) {
            float4 v = *(const float4*)&qp[d4 * 4];
            Qr[i][d4 * 4 + 0] = v.x * INV_SCALE;  // prescale -> exp(score) direct
            Qr[i][d4 * 4 + 1] = v.y * INV_SCALE;
            Qr[i][d4 * 4 + 2] = v.z * INV_SCALE;
            Qr[i][d4 * 4 + 3] = v.w * INV_SCALE;
        }
        ssum[i] = 0.f;
        #pragma unroll
        for (int d = 0; d < 16; ++d) outv[i][d] = 0.f;
    }

    const int rr = tid >> 3;          // 0..63
    const int c8 = (tid & 7) * 8;     // 0..56

    for (int t0 = 0; t0 < SP; t0 += 64) {
        __syncthreads();
        int nr = idx[p * SP + t0 + rr];
        const float* kp = &K[(size_t)nr * HDIM + h * DH + c8];
        const float* vp = &V[(size_t)nr * HDIM + h * DH + c8];
        *(float4*)&Ks[rr][c8]     = *(const float4*)&kp[0];
        *(float4*)&Ks[rr][c8 + 4] = *(const float4*)&kp[4];
        *(float4*)&Vs[rr][c8]     = *(const float4*)&vp[0];
        *(float4*)&Vs[rr][c8 + 4] = *(const float4*)&vp[4];
        __syncthreads();

        #pragma unroll 2
        for (int j = 0; j < 64; ++j) {
            float kk[16];
            #pragma unroll
            for (int d4 = 0; d4 < 4; ++d4)
                *(float4*)&kk[d4 * 4] = *(const float4*)&Ks[j][dq * 16 + d4 * 4];
            float s0 = 0.f, s1 = 0.f, s2 = 0.f, s3 = 0.f;
            #pragma unroll
            for (int d = 0; d < 16; ++d) {
                s0 += Qr[0][d] * kk[d];
                s1 += Qr[1][d] * kk[d];
                s2 += Qr[2][d] * kk[d];
                s3 += Qr[3][d] * kk[d];
            }
            s0 += __shfl_xor(s0, 1); s0 += __shfl_xor(s0, 2);
            s1 += __shfl_xor(s1, 1); s1 += __shfl_xor(s1, 2);
            s2 += __shfl_xor(s2, 1); s2 += __shfl_xor(s2, 2);
            s3 += __shfl_xor(s3, 1); s3 += __shfl_xor(s3, 2);

            float vv[16];
            #pragma unroll
            for (int d4 = 0; d4 < 4; ++d4)
                *(float4*)&vv[d4 * 4] = *(const float4*)&Vs[j][dq * 16 + d4 * 4];

            float p0 = __expf(s0), p1 = __expf(s1), p2 = __expf(s2), p3 = __expf(s3);
            ssum[0] += p0; ssum[1] += p1; ssum[2] += p2; ssum[3] += p3;
            #pragma unroll
            for (int d = 0; d < 16; ++d) {
                outv[0][d] += p0 * vv[d];
                outv[1][d] += p1 * vv[d];
                outv[2][d] += p2 * vv[d];
                outv[3][d] += p3 * vv[d];
            }
        }
    }

    const float al = alpha_logit[0], bw = bweight[0];
    #pragma unroll
    for (int i = 0; i < 4; ++i) {
        float a = 1.f / (1.f + __expf(-(al + bw * bscore[nq[i]])));
        float wgt = a * 0.25f / ssum[i];
        #pragma unroll
        for (int d = 0; d < 16; ++d)
            atomicAdd(&dout[(size_t)nq[i] * DH + dq * 16 + d], outv[i][d] * wgt);
    }
}

// ---------------------------------------------------------------------------
// Kernel D: global cross-attention over 256 reps, fused (1-alpha)*mean_h.
// grid (128 token-tiles, 4 heads), block 256.  Reps tiled 128-at-a-time in
// 64 KB LDS; no-max online accumulation across the 2 tiles.
// ---------------------------------------------------------------------------
__global__ __launch_bounds__(256) void global_attn(
    const float* __restrict__ Q,
    const float* __restrict__ reps_k, const float* __restrict__ reps_v,
    const float* __restrict__ bscore,
    const float* __restrict__ alpha_logit, const float* __restrict__ bweight,
    float* __restrict__ dout)
{
    const int tile = blockIdx.x, h = blockIdx.y;
    const int tid = threadIdx.x;
    const int dq = tid & 3;       // dim quarter
    const int tq = tid >> 2;      // 0..63

    __shared__ float rk[128][64];
    __shared__ float rv[128][64];

    int ntok[4];
    float Qr[4][16], outv[4][16], ssum[4];
    #pragma unroll
    for (int i = 0; i < 4; ++i) {
        ntok[i] = tile * 256 + tq + 64 * i;
        const float* qp = &Q[(size_t)ntok[i] * HDIM + h * DH + dq * 16];
        #pragma unroll
        for (int d4 = 0; d4 < 4; ++d4) {
            float4 v = *(const float4*)&qp[d4 * 4];
            Qr[i][d4 * 4 + 0] = v.x * INV_SCALE;
            Qr[i][d4 * 4 + 1] = v.y * INV_SCALE;
            Qr[i][d4 * 4 + 2] = v.z * INV_SCALE;
            Qr[i][d4 * 4 + 3] = v.w * INV_SCALE;
        }
        ssum[i] = 0.f;
        #pragma unroll
        for (int d = 0; d < 16; ++d) outv[i][d] = 0.f;
    }

    for (int t0 = 0; t0 < NREPS; t0 += 128) {
        __syncthreads();
        #pragma unroll
        for (int it = 0; it < 8; ++it) {
            int fidx = tid + 256 * it;      // 0..2047 float4 slots
            int rrow = fidx >> 4;           // 0..127
            int d4   = (fidx & 15) * 4;
            *(float4*)&rk[rrow][d4] = *(const float4*)&reps_k[(size_t)(t0 + rrow) * HDIM + h * DH + d4];
            *(float4*)&rv[rrow][d4] = *(const float4*)&reps_v[(size_t)(t0 + rrow) * HDIM + h * DH + d4];
        }
        __syncthreads();

        #pragma unroll 2
        for (int j = 0; j < 128; ++j) {
            float kk[16];
            #pragma unroll
            for (int d4 = 0; d4 < 4; ++d4)
                *(float4*)&kk[d4 * 4] = *(const float4*)&rk[j][dq * 16 + d4 * 4];
            float s0 = 0.f, s1 = 0.f, s2 = 0.f, s3 = 0.f;
            #pragma unroll
            for (int d = 0; d < 16; ++d) {
                s0 += Qr[0][d] * kk[d];
                s1 += Qr[1][d] * kk[d];
                s2 += Qr[2][d] * kk[d];
                s3 += Qr[3][d] * kk[d];
            }
            s0 += __shfl_xor(s0, 1); s0 += __shfl_xor(s0, 2);
            s1 += __shfl_xor(s1, 1); s1 += __shfl_xor(s1, 2);
            s2 += __shfl_xor(s2, 1); s2 += __shfl_xor(s2, 2);
            s3 += __shfl_xor(s3, 1); s3 += __shfl_xor(s3, 2);

            float vv[16];
            #pragma unroll
            for (int d4 = 0; d4 < 4; ++d4)
                *(float4*)&vv[d4 * 4] = *(const float4*)&rv[j][dq * 16 + d4 * 4];

            float p0 = __expf(s0), p1 = __expf(s1), p2 = __expf(s2), p3 = __expf(s3);
            ssum[0] += p0; ssum[1] += p1; ssum[2] += p2; ssum[3] += p3;
            #pragma unroll
            for (int d = 0; d < 16; ++d) {
                outv[0][d] += p0 * vv[d];
                outv[1][d] += p1 * vv[d];
                outv[2][d] += p2 * vv[d];
                outv[3][d] += p3 * vv[d];
            }
        }
    }

    const float al = alpha_logit[0], bw = bweight[0];
    #pragma unroll
    for (int i = 0; i < 4; ++i) {
        float a = 1.f / (1.f + __expf(-(al + bw * bscore[ntok[i]])));
        float wgt = (1.f - a) * 0.25f / ssum[i];
        #pragma unroll
        for (int d = 0; d < 16; ++d)
            atomicAdd(&dout[(size_t)ntok[i] * DH + dq * 16 + d], outv[i][d] * wgt);
    }
}

// ---------------------------------------------------------------------------
// Kernel E: += beta * mean_h(V).  grid 8192, block 256.
// ---------------------------------------------------------------------------
__global__ __launch_bounds__(256) void self_combine(
    const float* __restrict__ V, const float* __restrict__ beta_logit,
    float* __restrict__ dout)
{
    const int i = blockIdx.x * 256 + threadIdx.x;   // over N*64
    const int n = i >> 6, d = i & 63;
    const float beta = 2.f / (1.f + __expf(-beta_logit[0]));
    const size_t b = (size_t)n * HDIM + d;
    float s = V[b] + V[b + 64] + V[b + 128] + V[b + 192];
    dout[i] += beta * 0.25f * s;
}

// ---------------------------------------------------------------------------
extern "C" void kernel_launch(void* const* d_in, const int* in_sizes, int n_in,
                              void* d_out, int out_size, void* d_ws, size_t ws_size,
                              hipStream_t stream)
{
    (void)in_sizes; (void)n_in; (void)ws_size;
    const float* x      = (const float*)d_in[0];
    const int*   idx    = (const int*)d_in[1];
    const float* bscore = (const float*)d_in[2];
    const float* Wq = (const float*)d_in[3]; const float* bq = (const float*)d_in[4];
    const float* Wk = (const float*)d_in[5]; const float* bk = (const float*)d_in[6];
    const float* Wv = (const float*)d_in[7]; const float* bv = (const float*)d_in[8];
    const float* seeds = (const float*)d_in[9];
    const float* al = (const float*)d_in[10];
    const float* bw = (const float*)d_in[11];
    const float* bl = (const float*)d_in[12];
    float* out = (float*)d_out;
    float* ws  = (float*)d_ws;

    const size_t NM_ = (size_t)N_TOK * HDIM;
    float* Q      = ws;
    float* K      = ws + NM_;
    float* V      = ws + 2 * NM_;
    float* reps_k = ws + 3 * NM_;
    float* reps_v = reps_k + (size_t)NREPS * HDIM;

    hipMemsetAsync(d_out, 0, (size_t)out_size * sizeof(float), stream);

    qkv_gemm   <<<dim3(512, 4, 3), 256, 0, stream>>>(x, Wq, bq, Wk, bk, Wv, bv, Q, K, V);
    pool_reps  <<<dim3(NP, NH),    512, 0, stream>>>(K, V, idx, seeds, reps_k, reps_v);
    local_attn <<<dim3(NP, NH),    512, 0, stream>>>(Q, K, V, idx, bscore, al, bw, out);
    global_attn<<<dim3(128, NH),   256, 0, stream>>>(Q, reps_k, reps_v, bscore, al, bw, out);
    self_combine<<<8192, 256, 0, stream>>>(V, bl, out);
}

// Round 2
// 631.490 us; speedup vs baseline: 2.6823x; 2.6823x over previous
//
#include <hip/hip_runtime.h>
#include <hip/hip_bf16.h>

#define N_TOK 32768
#define INC   256     // input channels
#define HDIM  256     // H*D
#define NH    4
#define DH    64
#define NP    64      // partitions
#define SP    512     // partition size
#define NM    4       // pool seeds
#define NREPS 256     // P*M
#define INV_SCALE 0.125f

typedef __attribute__((ext_vector_type(8))) __bf16 bf16x8;
typedef __attribute__((ext_vector_type(4))) float  f32x4;

static __device__ __forceinline__ ushort f2bf(float f) {
    __hip_bfloat16 h = __float2bfloat16(f);
    return *reinterpret_cast<ushort*>(&h);
}
static __device__ __forceinline__ float bf2f(ushort u) {
    return __uint_as_float(((uint)u) << 16);
}

// ---------------------------------------------------------------------------
// Kernel A: QKV projection.  C = x @ W^T + b.  fp32 math (m33-style tile),
// emits bf16 Q/K/V for the MFMA attention stages; fp32 V kept for x_self.
// grid (512 row-tiles, 4 col-tiles, 3 matrices), block 256.
// ---------------------------------------------------------------------------
__global__ __launch_bounds__(256) void qkv_gemm(
    const float* __restrict__ x,
    const float* __restrict__ Wq, const float* __restrict__ bq,
    const float* __restrict__ Wk, const float* __restrict__ bk,
    const float* __restrict__ Wv, const float* __restrict__ bv,
    ushort* __restrict__ Qb, ushort* __restrict__ Kb, ushort* __restrict__ Vb,
    float* __restrict__ Vf)
{
    const float* W; const float* bias; ushort* outb; float* outf = nullptr;
    if (blockIdx.z == 0)      { W = Wq; bias = bq; outb = Qb; }
    else if (blockIdx.z == 1) { W = Wk; bias = bk; outb = Kb; }
    else                      { W = Wv; bias = bv; outb = Vb; outf = Vf; }

    __shared__ float xs[64][36];
    __shared__ float wsh[64][36];

    const int rowBase = blockIdx.x * 64;
    const int colBase = blockIdx.y * 64;
    const int tid = threadIdx.x;
    const int r = tid >> 4;
    const int c = tid & 15;

    float acc[4][4];
    #pragma unroll
    for (int a = 0; a < 4; ++a)
        #pragma unroll
        for (int b = 0; b < 4; ++b) acc[a][b] = 0.f;

    for (int k0 = 0; k0 < INC; k0 += 32) {
        __syncthreads();
        #pragma unroll
        for (int it = 0; it < 2; ++it) {
            int fidx = tid + 256 * it;
            int m  = fidx >> 3;
            int k4 = (fidx & 7) * 4;
            *(float4*)&xs[m][k4]  = *(const float4*)&x[(size_t)(rowBase + m) * INC + k0 + k4];
            *(float4*)&wsh[m][k4] = *(const float4*)&W[(size_t)(colBase + m) * INC + k0 + k4];
        }
        __syncthreads();
        #pragma unroll
        for (int kk = 0; kk < 32; kk += 4) {
            float4 xa[4], wb[4];
            #pragma unroll
            for (int a = 0; a < 4; ++a) xa[a] = *(const float4*)&xs[r + 16 * a][kk];
            #pragma unroll
            for (int b = 0; b < 4; ++b) wb[b] = *(const float4*)&wsh[c + 16 * b][kk];
            #pragma unroll
            for (int a = 0; a < 4; ++a)
                #pragma unroll
                for (int b = 0; b < 4; ++b)
                    acc[a][b] += xa[a].x * wb[b].x + xa[a].y * wb[b].y
                               + xa[a].z * wb[b].z + xa[a].w * wb[b].w;
        }
    }

    float bvv[4];
    #pragma unroll
    for (int b = 0; b < 4; ++b) bvv[b] = bias[colBase + c + 16 * b];
    #pragma unroll
    for (int a = 0; a < 4; ++a) {
        size_t row = (size_t)(rowBase + r + 16 * a) * HDIM;
        #pragma unroll
        for (int b = 0; b < 4; ++b) {
            float v = acc[a][b] + bvv[b];
            outb[row + colBase + c + 16 * b] = f2bf(v);
            if (outf) outf[row + colBase + c + 16 * b] = v;
        }
    }
}

// ---------------------------------------------------------------------------
// Kernel C: seed pooling -> bf16 reps.  grid (64,4), block 512. fp32 math on
// bf16 inputs (reps get rounded to bf16 anyway for the MFMA global stage).
// ---------------------------------------------------------------------------
__global__ __launch_bounds__(512) void pool_reps(
    const ushort* __restrict__ Kb, const ushort* __restrict__ Vb,
    const int* __restrict__ idx, const float* __restrict__ seeds,
    ushort* __restrict__ reps_k, ushort* __restrict__ reps_v)
{
    const int p = blockIdx.x, h = blockIdx.y;
    const int tid = threadIdx.x;
    __shared__ float pexp[NM][SP];
    __shared__ float sums[NM];
    __shared__ float sred[NM][8];
    __shared__ float sd[NM][DH];
    __shared__ int   sidx[SP];

    if (tid < NM * DH) {
        int m = tid >> 6, d = tid & 63;
        sd[m][d] = seeds[(size_t)(m * NH + h) * DH + d];
    }
    sidx[tid] = idx[p * SP + tid];
    __syncthreads();

    const int n_s = sidx[tid];
    float kr[64];
    #pragma unroll
    for (int c = 0; c < 8; ++c) {
        int4 raw = *(const int4*)&Kb[(size_t)n_s * HDIM + h * DH + c * 8];
        const ushort* u = (const ushort*)&raw;
        #pragma unroll
        for (int j = 0; j < 8; ++j) kr[c * 8 + j] = bf2f(u[j]);
    }

    float e[NM];
    #pragma unroll
    for (int m = 0; m < NM; ++m) {
        float s = 0.f;
        #pragma unroll
        for (int d = 0; d < 64; ++d) s += kr[d] * sd[m][d];
        e[m] = __expf(s * INV_SCALE);
        pexp[m][tid] = e[m];
    }
    const int lane = tid & 63, w = tid >> 6;
    #pragma unroll
    for (int m = 0; m < NM; ++m) {
        float v = e[m];
        #pragma unroll
        for (int off = 32; off >= 1; off >>= 1) v += __shfl_xor(v, off);
        if (lane == 0) sred[m][w] = v;
    }
    __syncthreads();
    if (tid < NM) {
        float s = 0.f;
        #pragma unroll
        for (int i = 0; i < 8; ++i) s += sred[tid][i];
        sums[tid] = s;
    }
    __syncthreads();

    const int m = w >> 1, kv = w & 1, d = lane;
    const ushort* src = kv ? Vb : Kb;
    float acc = 0.f;
    #pragma unroll 4
    for (int s = 0; s < SP; ++s)
        acc += pexp[m][s] * bf2f(src[(size_t)sidx[s] * HDIM + h * DH + d]);
    ushort* dst = kv ? reps_v : reps_k;
    dst[(size_t)(p * NM + m) * HDIM + h * DH + d] = f2bf(acc / sums[m]);
}

// ---------------------------------------------------------------------------
// Unified MFMA attention (local GATHER=1 over 512 partition keys, global
// GATHER=0 over 256 reps).  Block = 4 waves x 32 queries = 128 queries.
// Swapped QK^T (A=K, B=Q -> S^T): C/D col = query = lane&15 so the softmax
// sum, P-write (packed b64) and output normalization are all layout-aligned.
// PV: out^T = V^T x P^T.  All LDS tiles XOR-swizzled (chunk ^= row&7).
// ---------------------------------------------------------------------------
template<int GATHER>
__global__ __launch_bounds__(256, 2) void attn_mfma(
    const ushort* __restrict__ Qb, const ushort* __restrict__ Kb,
    const ushort* __restrict__ Vb,
    const int* __restrict__ idx, const float* __restrict__ bscore,
    const float* __restrict__ alpha_logit, const float* __restrict__ bweight,
    float* __restrict__ dout, int nkeys)
{
    const int h = blockIdx.y;
    const int tid  = threadIdx.x;
    const int wave = tid >> 6;
    const int lane = tid & 63;
    const int ln = lane & 15;       // MFMA col index
    const int lg = lane >> 4;       // MFMA k-group

    int p = 0, qc = 0;
    if (GATHER) { p = blockIdx.x >> 2; qc = blockIdx.x & 3; }

    __shared__ ushort Ks[128 * 64];       // [key][dim] swizzled, 16 KB
    __shared__ ushort Vt[64 * 128];       // [dim][key] swizzled, 16 KB
    __shared__ ushort Pb[4][32 * 128];    // per-wave [q][key] swizzled, 32 KB

    // --- Q fragments (held in regs for the whole kernel) ---
    bf16x8 qf[2][2];
    int tok[2];
    #pragma unroll
    for (int qt = 0; qt < 2; ++qt) {
        int qj = wave * 32 + qt * 16 + ln;
        int t  = GATHER ? idx[p * SP + qc * 128 + qj] : blockIdx.x * 128 + qj;
        tok[qt] = t;
        #pragma unroll
        for (int kc = 0; kc < 2; ++kc)
            qf[qt][kc] = *(const bf16x8*)&Qb[(size_t)t * HDIM + h * DH + kc * 32 + lg * 8];
    }

    f32x4 oa[4][2];
    #pragma unroll
    for (int dt = 0; dt < 4; ++dt)
        #pragma unroll
        for (int qt = 0; qt < 2; ++qt) oa[dt][qt] = (f32x4){0.f, 0.f, 0.f, 0.f};
    float ssum[2] = {0.f, 0.f};

    for (int kt0 = 0; kt0 < nkeys; kt0 += 128) {
        __syncthreads();
        // --- stage K tile: [key][dim], 16B chunks, swizzled ---
        #pragma unroll
        for (int i = 0; i < 4; ++i) {
            int c0 = tid + 256 * i;
            int key = c0 >> 3, dc = c0 & 7;
            int row = GATHER ? idx[p * SP + kt0 + key] : (kt0 + key);
            int4 val = *(const int4*)&Kb[(size_t)row * HDIM + h * DH + dc * 8];
            *(int4*)&Ks[key * 64 + ((dc ^ (key & 7)) << 3)] = val;
        }
        // --- stage V^T tile: [dim][key], packed key-pairs, swizzled ---
        #pragma unroll
        for (int i = 0; i < 2; ++i) {
            int a = tid + 256 * i;
            int kp = a & 63, dc = a >> 6;
            int r0 = GATHER ? idx[p * SP + kt0 + 2 * kp]     : (kt0 + 2 * kp);
            int r1 = GATHER ? idx[p * SP + kt0 + 2 * kp + 1] : (kt0 + 2 * kp + 1);
            int4 v0 = *(const int4*)&Vb[(size_t)r0 * HDIM + h * DH + dc * 8];
            int4 v1 = *(const int4*)&Vb[(size_t)r1 * HDIM + h * DH + dc * 8];
            const ushort* u0 = (const ushort*)&v0;
            const ushort* u1 = (const ushort*)&v1;
            #pragma unroll
            for (int j = 0; j < 8; ++j) {
                int d = dc * 8 + j;
                uint pk = (uint)u0[j] | ((uint)u1[j] << 16);
                *(uint*)&Vt[d * 128 + (((kp >> 2) ^ (d & 7)) << 3) + (kp & 3) * 2] = pk;
            }
        }
        __syncthreads();

        // --- scores: S^T = K x Q^T, exp, pack to P ---
        #pragma unroll
        for (int ktile = 0; ktile < 8; ++ktile) {
            int kr = ktile * 16 + ln;
            bf16x8 ka0 = *(const bf16x8*)&Ks[kr * 64 + ((lg       ^ (kr & 7)) << 3)];
            bf16x8 ka1 = *(const bf16x8*)&Ks[kr * 64 + (((4 + lg) ^ (kr & 7)) << 3)];
            #pragma unroll
            for (int qt = 0; qt < 2; ++qt) {
                f32x4 s = (f32x4){0.f, 0.f, 0.f, 0.f};
                s = __builtin_amdgcn_mfma_f32_16x16x32_bf16(ka0, qf[qt][0], s, 0, 0, 0);
                s = __builtin_amdgcn_mfma_f32_16x16x32_bf16(ka1, qf[qt][1], s, 0, 0, 0);
                float p0 = __expf(s[0] * INV_SCALE);
                float p1 = __expf(s[1] * INV_SCALE);
                float p2 = __expf(s[2] * INV_SCALE);
                float p3 = __expf(s[3] * INV_SCALE);
                ssum[qt] += (p0 + p1) + (p2 + p3);
                uint lo = (uint)f2bf(p0) | ((uint)f2bf(p1) << 16);
                uint hi = (uint)f2bf(p2) | ((uint)f2bf(p3) << 16);
                int q  = qt * 16 + ln;
                int k0 = ktile * 16 + lg * 4;
                uint2 pk; pk.x = lo; pk.y = hi;
                *(uint2*)&Pb[wave][q * 128 + (((k0 >> 3) ^ (q & 7)) << 3) + (k0 & 7)] = pk;
            }
        }

        // --- PV: out^T += V^T x P^T ---
        bf16x8 pf[2][4];
        #pragma unroll
        for (int qt = 0; qt < 2; ++qt) {
            int q = qt * 16 + ln;
            #pragma unroll
            for (int kc = 0; kc < 4; ++kc) {
                int k0 = kc * 32 + lg * 8;
                pf[qt][kc] = *(const bf16x8*)&Pb[wave][q * 128 + (((k0 >> 3) ^ (q & 7)) << 3)];
            }
        }
        #pragma unroll
        for (int dt = 0; dt < 4; ++dt) {
            int d = dt * 16 + ln;
            bf16x8 vf[4];
            #pragma unroll
            for (int kc = 0; kc < 4; ++kc) {
                int k0 = kc * 32 + lg * 8;
                vf[kc] = *(const bf16x8*)&Vt[d * 128 + (((k0 >> 3) ^ (d & 7)) << 3)];
            }
            #pragma unroll
            for (int qt = 0; qt < 2; ++qt)
                #pragma unroll
                for (int kc = 0; kc < 4; ++kc)
                    oa[dt][qt] = __builtin_amdgcn_mfma_f32_16x16x32_bf16(
                        vf[kc], pf[qt][kc], oa[dt][qt], 0, 0, 0);
        }
    }

    // --- normalize + fused alpha/(1-alpha) weighting, atomic accumulate ---
    const float al = alpha_logit[0], bw = bweight[0];
    #pragma unroll
    for (int qt = 0; qt < 2; ++qt) {
        float s = ssum[qt];
        s += __shfl_xor(s, 16);
        s += __shfl_xor(s, 32);
        float a = 1.f / (1.f + __expf(-(al + bw * bscore[tok[qt]])));
        float wgt = (GATHER ? a : (1.f - a)) * 0.25f / s;
        #pragma unroll
        for (int dt = 0; dt < 4; ++dt) {
            #pragma unroll
            for (int r = 0; r < 4; ++r)
                atomicAdd(&dout[(size_t)tok[qt] * DH + dt * 16 + lg * 4 + r],
                          oa[dt][qt][r] * wgt);
        }
    }
}

// ---------------------------------------------------------------------------
// Kernel E: += beta * mean_h(V).  grid 8192, block 256.
// ---------------------------------------------------------------------------
__global__ __launch_bounds__(256) void self_combine(
    const float* __restrict__ V, const float* __restrict__ beta_logit,
    float* __restrict__ dout)
{
    const int i = blockIdx.x * 256 + threadIdx.x;
    const int n = i >> 6, d = i & 63;
    const float beta = 2.f / (1.f + __expf(-beta_logit[0]));
    const size_t b = (size_t)n * HDIM + d;
    float s = V[b] + V[b + 64] + V[b + 128] + V[b + 192];
    dout[i] += beta * 0.25f * s;
}

// ---------------------------------------------------------------------------
extern "C" void kernel_launch(void* const* d_in, const int* in_sizes, int n_in,
                              void* d_out, int out_size, void* d_ws, size_t ws_size,
                              hipStream_t stream)
{
    (void)in_sizes; (void)n_in; (void)ws_size;
    const float* x      = (const float*)d_in[0];
    const int*   idx    = (const int*)d_in[1];
    const float* bscore = (const float*)d_in[2];
    const float* Wq = (const float*)d_in[3]; const float* bq = (const float*)d_in[4];
    const float* Wk = (const float*)d_in[5]; const float* bk = (const float*)d_in[6];
    const float* Wv = (const float*)d_in[7]; const float* bv = (const float*)d_in[8];
    const float* seeds = (const float*)d_in[9];
    const float* al = (const float*)d_in[10];
    const float* bw = (const float*)d_in[11];
    const float* bl = (const float*)d_in[12];
    float* out = (float*)d_out;

    const size_t NE = (size_t)N_TOK * HDIM;    // 8,388,608
    float*  Vf = (float*)d_ws;
    ushort* Qb = (ushort*)(Vf + NE);
    ushort* Kb = Qb + NE;
    ushort* Vb = Kb + NE;
    ushort* repkb = Vb + NE;
    ushort* repvb = repkb + (size_t)NREPS * HDIM;

    hipMemsetAsync(d_out, 0, (size_t)out_size * sizeof(float), stream);

    qkv_gemm<<<dim3(512, 4, 3), 256, 0, stream>>>(x, Wq, bq, Wk, bk, Wv, bv,
                                                  Qb, Kb, Vb, Vf);
    pool_reps<<<dim3(NP, NH), 512, 0, stream>>>(Kb, Vb, idx, seeds, repkb, repvb);
    attn_mfma<1><<<dim3(256, NH), 256, 0, stream>>>(Qb, Kb, Vb, idx, bscore,
                                                    al, bw, out, SP);
    attn_mfma<0><<<dim3(256, NH), 256, 0, stream>>>(Qb, repkb, repvb, idx, bscore,
                                                    al, bw, out, NREPS);
    self_combine<<<8192, 256, 0, stream>>>(Vf, bl, out);
}

// Round 4
// 436.311 us; speedup vs baseline: 3.8822x; 1.4473x over previous
//
#include <hip/hip_runtime.h>
#include <hip/hip_bf16.h>

#define N_TOK 32768
#define INC   256     // input channels
#define HDIM  256     // H*D
#define NH    4
#define DH    64
#define NP    64      // partitions
#define SP    512     // partition size
#define NM    4       // pool seeds
#define NREPS 256     // P*M
#define INV_SCALE 0.125f

typedef __attribute__((ext_vector_type(8))) __bf16 bf16x8;
typedef __attribute__((ext_vector_type(4))) float  f32x4;

static __device__ __forceinline__ ushort f2bf(float f) {
    __hip_bfloat16 h = __float2bfloat16(f);
    return *reinterpret_cast<ushort*>(&h);
}
static __device__ __forceinline__ float bf2f(ushort u) {
    return __uint_as_float(((uint)u) << 16);
}

#define GL_LDS16(g, l) __builtin_amdgcn_global_load_lds( \
    (const __attribute__((address_space(1))) unsigned int*)(g), \
    (__attribute__((address_space(3))) unsigned int*)(l), 16, 0, 0)

// ---------------------------------------------------------------------------
// Kernel 0: fp32 -> bf16 conversion of x and the 3 weight matrices, plus
// WvAvg[d][k] = 0.25 * sum_h Wv[h*64+d][k] (fp32, for the exact x_self path).
// grid 4256 x 256.
// ---------------------------------------------------------------------------
__global__ __launch_bounds__(256) void conv_bf16(
    const float* __restrict__ x,
    const float* __restrict__ Wq, const float* __restrict__ Wk,
    const float* __restrict__ Wv,
    ushort* __restrict__ xb, ushort* __restrict__ Wb,
    float* __restrict__ WvAvg)
{
    const int b = blockIdx.x, tid = threadIdx.x;
    if (b < 4096) {                       // x: 8.4M elements, 8 per thread
        size_t base = (size_t)b * 2048 + tid * 8;
        float4 a = *(const float4*)&x[base];
        float4 c = *(const float4*)&x[base + 4];
        ushort u[8] = {f2bf(a.x), f2bf(a.y), f2bf(a.z), f2bf(a.w),
                       f2bf(c.x), f2bf(c.y), f2bf(c.z), f2bf(c.w)};
        *(int4*)&xb[base] = *(int4*)u;
    } else if (b < 4192) {                // weights: 3 x 65536
        int wb = b - 4096;                // 0..95
        const float* W = (wb < 32) ? Wq : (wb < 64) ? Wk : Wv;
        int mat = wb >> 5;
        size_t off = (size_t)(wb & 31) * 2048 + tid * 8;
        float4 a = *(const float4*)&W[off];
        float4 c = *(const float4*)&W[off + 4];
        ushort u[8] = {f2bf(a.x), f2bf(a.y), f2bf(a.z), f2bf(a.w),
                       f2bf(c.x), f2bf(c.y), f2bf(c.z), f2bf(c.w)};
        *(int4*)&Wb[(size_t)mat * 65536 + off] = *(int4*)u;
    } else {                              // WvAvg: 64 x 256 fp32
        int i = (b - 4192) * 256 + tid;
        int d = i >> 8, k = i & 255;
        WvAvg[i] = 0.25f * (Wv[(size_t)d * 256 + k] +
                            Wv[(size_t)(d + 64) * 256 + k] +
                            Wv[(size_t)(d + 128) * 256 + k] +
                            Wv[(size_t)(d + 192) * 256 + k]);
    }
}

// ---------------------------------------------------------------------------
// Kernel A: QKV projection, bf16 MFMA.  C[128x128] per block, 4 waves each
// 32x128.  BK=64, global_load_lds w=16 with pre-swizzled global source so
// swizzled ds_read_b128 fragment reads are conflict-free.  Epilogue stores
// via LDS transpose -> b128 coalesced global writes.
// grid (256 row-tiles, 6 = 3 matrices x 2 col-halves), block 256.
// ---------------------------------------------------------------------------
__global__ __launch_bounds__(256, 2) void qkv_mfma(
    const ushort* __restrict__ xb, const ushort* __restrict__ Wb,
    const float* __restrict__ bq, const float* __restrict__ bk,
    const float* __restrict__ bv,
    ushort* __restrict__ Qb, ushort* __restrict__ Kb, ushort* __restrict__ Vb)
{
    const int bx = blockIdx.x;
    const int by = blockIdx.y;
    const int mat = by >> 1, nh = by & 1;
    const ushort* W = Wb + (size_t)mat * 65536 + (size_t)nh * 128 * 256;
    const float* bias = ((mat == 0) ? bq : (mat == 1) ? bk : bv) + nh * 128;
    ushort* outp = (mat == 0) ? Qb : (mat == 1) ? Kb : Vb;
    const int rowBase = bx * 128;
    const int colBase = nh * 128;

    __shared__ ushort As[128 * 64];
    __shared__ ushort Bs[128 * 64];
    __shared__ ushort Cs[4][32][136];   // epilogue transpose buffer

    const int tid = threadIdx.x, wave = tid >> 6, lane = tid & 63;
    const int ln = lane & 15, lg = lane >> 4;

    f32x4 acc[2][8];
    #pragma unroll
    for (int mt = 0; mt < 2; ++mt)
        #pragma unroll
        for (int nt = 0; nt < 8; ++nt) acc[mt][nt] = (f32x4){0.f, 0.f, 0.f, 0.f};

    for (int k0 = 0; k0 < 256; k0 += 64) {
        __syncthreads();
        #pragma unroll
        for (int i = 0; i < 4; ++i) {
            int r0 = wave * 32 + i * 8;
            int r  = r0 + (lane >> 3);
            int cc = (lane & 7) ^ (r & 7);       // inverse-swizzled source chunk
            GL_LDS16(&xb[(size_t)(rowBase + r) * 256 + k0 + cc * 8], &As[r0 * 64]);
            GL_LDS16(&W[(size_t)r * 256 + k0 + cc * 8], &Bs[r0 * 64]);
        }
        __syncthreads();

        bf16x8 af[2][2], bfr[8][2];
        #pragma unroll
        for (int mt = 0; mt < 2; ++mt)
            #pragma unroll
            for (int kk = 0; kk < 2; ++kk) {
                int row = wave * 32 + mt * 16 + ln;
                int ch  = (kk * 4 + lg) ^ (row & 7);
                af[mt][kk] = *(const bf16x8*)&As[row * 64 + ch * 8];
            }
        #pragma unroll
        for (int nt = 0; nt < 8; ++nt)
            #pragma unroll
            for (int kk = 0; kk < 2; ++kk) {
                int n  = nt * 16 + ln;
                int ch = (kk * 4 + lg) ^ (n & 7);
                bfr[nt][kk] = *(const bf16x8*)&Bs[n * 64 + ch * 8];
            }
        #pragma unroll
        for (int mt = 0; mt < 2; ++mt)
            #pragma unroll
            for (int nt = 0; nt < 8; ++nt)
                #pragma unroll
                for (int kk = 0; kk < 2; ++kk)
                    acc[mt][nt] = __builtin_amdgcn_mfma_f32_16x16x32_bf16(
                        af[mt][kk], bfr[nt][kk], acc[mt][nt], 0, 0, 0);
    }

    // epilogue: bias + bf16, transpose via LDS, coalesced b128 stores
    float bvv[8];
    #pragma unroll
    for (int nt = 0; nt < 8; ++nt) bvv[nt] = bias[nt * 16 + ln];
    #pragma unroll
    for (int mt = 0; mt < 2; ++mt)
        #pragma unroll
        for (int nt = 0; nt < 8; ++nt)
            #pragma unroll
            for (int r = 0; r < 4; ++r)
                Cs[wave][mt * 16 + lg * 4 + r][nt * 16 + ln] =
                    f2bf(acc[mt][nt][r] + bvv[nt]);
    __syncthreads();
    #pragma unroll
    for (int i = 0; i < 8; ++i) {
        int c = i * 64 + lane;
        int row = c >> 4, ch = c & 15;
        int4 v = *(const int4*)&Cs[wave][row][ch * 8];
        int outRow = rowBase + wave * 32 + row;
        *(int4*)&outp[(size_t)outRow * 256 + colBase + ch * 8] = v;
    }
}

// ---------------------------------------------------------------------------
// Kernel B: exact fp32 x_self path: dout = beta * (x @ WvAvg^T + bvAvg).
// Runs BEFORE the attention kernels (which atomicAdd on top); replaces the
// memset.  grid 512 x 256, 64 rows x 64 cols per block, 4x4 per thread.
// ---------------------------------------------------------------------------
__global__ __launch_bounds__(256) void xself_gemm(
    const float* __restrict__ x, const float* __restrict__ WvAvg,
    const float* __restrict__ bv, const float* __restrict__ beta_logit,
    float* __restrict__ dout)
{
    __shared__ float xs[64][68];
    __shared__ float wsh[64][68];
    const int rowBase = blockIdx.x * 64;
    const int tid = threadIdx.x;
    const int r = tid >> 4, c = tid & 15;

    float acc[4][4];
    #pragma unroll
    for (int a = 0; a < 4; ++a)
        #pragma unroll
        for (int b = 0; b < 4; ++b) acc[a][b] = 0.f;

    for (int k0 = 0; k0 < 256; k0 += 64) {
        __syncthreads();
        #pragma unroll
        for (int i = 0; i < 4; ++i) {
            int f = tid + 256 * i;
            int m = f >> 4, k4 = (f & 15) * 4;
            *(float4*)&xs[m][k4] = *(const float4*)&x[(size_t)(rowBase + m) * 256 + k0 + k4];
        }
        #pragma unroll
        for (int i = 0; i < 4; ++i) {
            int f = tid + 256 * i;
            int n = f >> 4, k4 = (f & 15) * 4;
            *(float4*)&wsh[n][k4] = *(const float4*)&WvAvg[(size_t)n * 256 + k0 + k4];
        }
        __syncthreads();
        #pragma unroll
        for (int kk = 0; kk < 64; kk += 2) {
            float2 a2[4], b2[4];
            #pragma unroll
            for (int a = 0; a < 4; ++a) a2[a] = *(const float2*)&xs[r + 16 * a][kk];
            #pragma unroll
            for (int b = 0; b < 4; ++b) b2[b] = *(const float2*)&wsh[c + 16 * b][kk];
            #pragma unroll
            for (int a = 0; a < 4; ++a)
                #pragma unroll
                for (int b = 0; b < 4; ++b)
                    acc[a][b] += a2[a].x * b2[b].x + a2[a].y * b2[b].y;
        }
    }

    const float beta = 2.f / (1.f + __expf(-beta_logit[0]));
    #pragma unroll
    for (int b = 0; b < 4; ++b) {
        int col = c + 16 * b;
        float bavg = 0.25f * (bv[col] + bv[col + 64] + bv[col + 128] + bv[col + 192]);
        #pragma unroll
        for (int a = 0; a < 4; ++a)
            dout[(size_t)(rowBase + r + 16 * a) * 64 + col] = beta * (acc[a][b] + bavg);
    }
}

// ---------------------------------------------------------------------------
// Kernel C: seed pooling -> bf16 reps.  grid (64,4), block 512.
// ---------------------------------------------------------------------------
__global__ __launch_bounds__(512) void pool_reps(
    const ushort* __restrict__ Kb, const ushort* __restrict__ Vb,
    const int* __restrict__ idx, const float* __restrict__ seeds,
    ushort* __restrict__ reps_k, ushort* __restrict__ reps_v)
{
    const int p = blockIdx.x, h = blockIdx.y;
    const int tid = threadIdx.x;
    __shared__ float pexp[NM][SP];
    __shared__ float sums[NM];
    __shared__ float sred[NM][8];
    __shared__ float sd[NM][DH];
    __shared__ int   sidx[SP];

    if (tid < NM * DH) {
        int m = tid >> 6, d = tid & 63;
        sd[m][d] = seeds[(size_t)(m * NH + h) * DH + d];
    }
    sidx[tid] = idx[p * SP + tid];
    __syncthreads();

    const int n_s = sidx[tid];
    float kr[64];
    #pragma unroll
    for (int c = 0; c < 8; ++c) {
        int4 raw = *(const int4*)&Kb[(size_t)n_s * HDIM + h * DH + c * 8];
        const ushort* u = (const ushort*)&raw;
        #pragma unroll
        for (int j = 0; j < 8; ++j) kr[c * 8 + j] = bf2f(u[j]);
    }

    float e[NM];
    #pragma unroll
    for (int m = 0; m < NM; ++m) {
        float s = 0.f;
        #pragma unroll
        for (int d = 0; d < 64; ++d) s += kr[d] * sd[m][d];
        e[m] = __expf(s * INV_SCALE);
        pexp[m][tid] = e[m];
    }
    const int lane = tid & 63, w = tid >> 6;
    #pragma unroll
    for (int m = 0; m < NM; ++m) {
        float v = e[m];
        #pragma unroll
        for (int off = 32; off >= 1; off >>= 1) v += __shfl_xor(v, off);
        if (lane == 0) sred[m][w] = v;
    }
    __syncthreads();
    if (tid < NM) {
        float s = 0.f;
        #pragma unroll
        for (int i = 0; i < 8; ++i) s += sred[tid][i];
        sums[tid] = s;
    }
    __syncthreads();

    const int m = w >> 1, kv = w & 1, d = lane;
    const ushort* src = kv ? Vb : Kb;
    float acc = 0.f;
    #pragma unroll 4
    for (int s = 0; s < SP; ++s)
        acc += pexp[m][s] * bf2f(src[(size_t)sidx[s] * HDIM + h * DH + d]);
    ushort* dst = kv ? reps_v : reps_k;
    dst[(size_t)(p * NM + m) * HDIM + h * DH + d] = f2bf(acc / sums[m]);
}

// ---------------------------------------------------------------------------
// Unified MFMA attention (local GATHER=1 over 512 partition keys, global
// GATHER=0 over 256 reps).  Block = 4 waves x 32 queries = 128 queries.
// ---------------------------------------------------------------------------
template<int GATHER>
__global__ __launch_bounds__(256, 2) void attn_mfma(
    const ushort* __restrict__ Qb, const ushort* __restrict__ Kb,
    const ushort* __restrict__ Vb,
    const int* __restrict__ idx, const float* __restrict__ bscore,
    const float* __restrict__ alpha_logit, const float* __restrict__ bweight,
    float* __restrict__ dout, int nkeys)
{
    const int h = blockIdx.y;
    const int tid  = threadIdx.x;
    const int wave = tid >> 6;
    const int lane = tid & 63;
    const int ln = lane & 15;
    const int lg = lane >> 4;

    int p = 0, qc = 0;
    if (GATHER) { p = blockIdx.x >> 2; qc = blockIdx.x & 3; }

    __shared__ ushort Ks[128 * 64];
    __shared__ ushort Vt[64 * 128];
    __shared__ ushort Pb[4][32 * 128];

    bf16x8 qf[2][2];
    int tok[2];
    #pragma unroll
    for (int qt = 0; qt < 2; ++qt) {
        int qj = wave * 32 + qt * 16 + ln;
        int t  = GATHER ? idx[p * SP + qc * 128 + qj] : blockIdx.x * 128 + qj;
        tok[qt] = t;
        #pragma unroll
        for (int kc = 0; kc < 2; ++kc)
            qf[qt][kc] = *(const bf16x8*)&Qb[(size_t)t * HDIM + h * DH + kc * 32 + lg * 8];
    }

    f32x4 oa[4][2];
    #pragma unroll
    for (int dt = 0; dt < 4; ++dt)
        #pragma unroll
        for (int qt = 0; qt < 2; ++qt) oa[dt][qt] = (f32x4){0.f, 0.f, 0.f, 0.f};
    float ssum[2] = {0.f, 0.f};

    for (int kt0 = 0; kt0 < nkeys; kt0 += 128) {
        __syncthreads();
        #pragma unroll
        for (int i = 0; i < 4; ++i) {
            int c0 = tid + 256 * i;
            int key = c0 >> 3, dc = c0 & 7;
            int row = GATHER ? idx[p * SP + kt0 + key] : (kt0 + key);
            int4 val = *(const int4*)&Kb[(size_t)row * HDIM + h * DH + dc * 8];
            *(int4*)&Ks[key * 64 + ((dc ^ (key & 7)) << 3)] = val;
        }
        #pragma unroll
        for (int i = 0; i < 2; ++i) {
            int a = tid + 256 * i;
            int kp = a & 63, dc = a >> 6;
            int r0 = GATHER ? idx[p * SP + kt0 + 2 * kp]     : (kt0 + 2 * kp);
            int r1 = GATHER ? idx[p * SP + kt0 + 2 * kp + 1] : (kt0 + 2 * kp + 1);
            int4 v0 = *(const int4*)&Vb[(size_t)r0 * HDIM + h * DH + dc * 8];
            int4 v1 = *(const int4*)&Vb[(size_t)r1 * HDIM + h * DH + dc * 8];
            const ushort* u0 = (const ushort*)&v0;
            const ushort* u1 = (const ushort*)&v1;
            #pragma unroll
            for (int j = 0; j < 8; ++j) {
                int d = dc * 8 + j;
                uint pk = (uint)u0[j] | ((uint)u1[j] << 16);
                *(uint*)&Vt[d * 128 + (((kp >> 2) ^ (d & 7)) << 3) + (kp & 3) * 2] = pk;
            }
        }
        __syncthreads();

        #pragma unroll
        for (int ktile = 0; ktile < 8; ++ktile) {
            int kr = ktile * 16 + ln;
            bf16x8 ka0 = *(const bf16x8*)&Ks[kr * 64 + ((lg       ^ (kr & 7)) << 3)];
            bf16x8 ka1 = *(const bf16x8*)&Ks[kr * 64 + (((4 + lg) ^ (kr & 7)) << 3)];
            #pragma unroll
            for (int qt = 0; qt < 2; ++qt) {
                f32x4 s = (f32x4){0.f, 0.f, 0.f, 0.f};
                s = __builtin_amdgcn_mfma_f32_16x16x32_bf16(ka0, qf[qt][0], s, 0, 0, 0);
                s = __builtin_amdgcn_mfma_f32_16x16x32_bf16(ka1, qf[qt][1], s, 0, 0, 0);
                float p0 = __expf(s[0] * INV_SCALE);
                float p1 = __expf(s[1] * INV_SCALE);
                float p2 = __expf(s[2] * INV_SCALE);
                float p3 = __expf(s[3] * INV_SCALE);
                ssum[qt] += (p0 + p1) + (p2 + p3);
                uint lo = (uint)f2bf(p0) | ((uint)f2bf(p1) << 16);
                uint hi = (uint)f2bf(p2) | ((uint)f2bf(p3) << 16);
                int q  = qt * 16 + ln;
                int k0 = ktile * 16 + lg * 4;
                uint2 pk; pk.x = lo; pk.y = hi;
                *(uint2*)&Pb[wave][q * 128 + (((k0 >> 3) ^ (q & 7)) << 3) + (k0 & 7)] = pk;
            }
        }

        bf16x8 pf[2][4];
        #pragma unroll
        for (int qt = 0; qt < 2; ++qt) {
            int q = qt * 16 + ln;
            #pragma unroll
            for (int kc = 0; kc < 4; ++kc) {
                int k0 = kc * 32 + lg * 8;
                pf[qt][kc] = *(const bf16x8*)&Pb[wave][q * 128 + (((k0 >> 3) ^ (q & 7)) << 3)];
            }
        }
        #pragma unroll
        for (int dt = 0; dt < 4; ++dt) {
            int d = dt * 16 + ln;
            bf16x8 vf[4];
            #pragma unroll
            for (int kc = 0; kc < 4; ++kc) {
                int k0 = kc * 32 + lg * 8;
                vf[kc] = *(const bf16x8*)&Vt[d * 128 + (((k0 >> 3) ^ (d & 7)) << 3)];
            }
            #pragma unroll
            for (int qt = 0; qt < 2; ++qt)
                #pragma unroll
                for (int kc = 0; kc < 4; ++kc)
                    oa[dt][qt] = __builtin_amdgcn_mfma_f32_16x16x32_bf16(
                        vf[kc], pf[qt][kc], oa[dt][qt], 0, 0, 0);
        }
    }

    const float al = alpha_logit[0], bw = bweight[0];
    #pragma unroll
    for (int qt = 0; qt < 2; ++qt) {
        float s = ssum[qt];
        s += __shfl_xor(s, 16);
        s += __shfl_xor(s, 32);
        float a = 1.f / (1.f + __expf(-(al + bw * bscore[tok[qt]])));
        float wgt = (GATHER ? a : (1.f - a)) * 0.25f / s;
        #pragma unroll
        for (int dt = 0; dt < 4; ++dt) {
            #pragma unroll
            for (int r = 0; r < 4; ++r)
                atomicAdd(&dout[(size_t)tok[qt] * DH + dt * 16 + lg * 4 + r],
                          oa[dt][qt][r] * wgt);
        }
    }
}

// ---------------------------------------------------------------------------
extern "C" void kernel_launch(void* const* d_in, const int* in_sizes, int n_in,
                              void* d_out, int out_size, void* d_ws, size_t ws_size,
                              hipStream_t stream)
{
    (void)in_sizes; (void)n_in; (void)ws_size; (void)out_size;
    const float* x      = (const float*)d_in[0];
    const int*   idx    = (const int*)d_in[1];
    const float* bscore = (const float*)d_in[2];
    const float* Wq = (const float*)d_in[3]; const float* bq = (const float*)d_in[4];
    const float* Wk = (const float*)d_in[5]; const float* bk = (const float*)d_in[6];
    const float* Wv = (const float*)d_in[7]; const float* bv = (const float*)d_in[8];
    const float* seeds = (const float*)d_in[9];
    const float* al = (const float*)d_in[10];
    const float* bw = (const float*)d_in[11];
    const float* bl = (const float*)d_in[12];
    float* out = (float*)d_out;

    const size_t NE = (size_t)N_TOK * HDIM;    // 8,388,608
    ushort* xb    = (ushort*)d_ws;
    ushort* Wb    = xb + NE;
    ushort* Qb    = Wb + 3 * 65536;
    ushort* Kb    = Qb + NE;
    ushort* Vb    = Kb + NE;
    ushort* repkb = Vb + NE;
    ushort* repvb = repkb + (size_t)NREPS * HDIM;
    float*  WvAvg = (float*)(repvb + (size_t)NREPS * HDIM);

    conv_bf16 <<<4256, 256, 0, stream>>>(x, Wq, Wk, Wv, xb, Wb, WvAvg);
    qkv_mfma  <<<dim3(256, 6), 256, 0, stream>>>(xb, Wb, bq, bk, bv, Qb, Kb, Vb);
    xself_gemm<<<512, 256, 0, stream>>>(x, WvAvg, bv, bl, out);
    pool_reps <<<dim3(NP, NH), 512, 0, stream>>>(Kb, Vb, idx, seeds, repkb, repvb);
    attn_mfma<1><<<dim3(256, NH), 256, 0, stream>>>(Qb, Kb, Vb, idx, bscore,
                                                    al, bw, out, SP);
    attn_mfma<0><<<dim3(256, NH), 256, 0, stream>>>(Qb, repkb, repvb, idx, bscore,
                                                    al, bw, out, NREPS);
}